// Round 1
// baseline (1998.200 us; speedup 1.0000x reference)
//
#include <hip/hip_runtime.h>

#define DIM 1024
#define HEADS 16
#define HEAD_DIM 64
#define SEQ 2048
#define BATCH 4
#define SCALE 0.125f
#define NEG_BIG (-1e30f)

// ---------------------------------------------------------------------------
// QKV projection: C[m,e] = sum_d X[m,d] * Wqkv[e,d]
// scattered into qkv_buf laid out as [3][b*16+h][s][64]
// ---------------------------------------------------------------------------
__global__ __launch_bounds__(256) void qkv_gemm(const float* __restrict__ X,
                                                const float* __restrict__ W,
                                                float* __restrict__ qkvbuf) {
    __shared__ float As[16][68];
    __shared__ float Bs[16][68];
    const int t  = threadIdx.x;
    const int m0 = blockIdx.y * 64;
    const int e0 = blockIdx.x * 64;
    const int ty = t >> 4, tx = t & 15;
    const int lr = t >> 2;           // 0..63 row within tile
    const int lk = (t & 3) * 4;      // 0,4,8,12 k offset (float4)

    float acc[4][4] = {};

    for (int k0 = 0; k0 < DIM; k0 += 16) {
        __syncthreads();
        const float4 av = *(const float4*)&X[(size_t)(m0 + lr) * DIM + k0 + lk];
        const float4 bv = *(const float4*)&W[(size_t)(e0 + lr) * DIM + k0 + lk];
        As[lk + 0][lr] = av.x; As[lk + 1][lr] = av.y;
        As[lk + 2][lr] = av.z; As[lk + 3][lr] = av.w;
        Bs[lk + 0][lr] = bv.x; Bs[lk + 1][lr] = bv.y;
        Bs[lk + 2][lr] = bv.z; Bs[lk + 3][lr] = bv.w;
        __syncthreads();
        #pragma unroll
        for (int kk = 0; kk < 16; ++kk) {
            const float4 a4 = *(const float4*)&As[kk][4 * ty];
            const float4 b4 = *(const float4*)&Bs[kk][4 * tx];
            const float a[4] = {a4.x, a4.y, a4.z, a4.w};
            const float b[4] = {b4.x, b4.y, b4.z, b4.w};
            #pragma unroll
            for (int i = 0; i < 4; ++i)
                #pragma unroll
                for (int j = 0; j < 4; ++j)
                    acc[i][j] = fmaf(a[i], b[j], acc[i][j]);
        }
    }

    #pragma unroll
    for (int i = 0; i < 4; ++i) {
        const int m = m0 + 4 * ty + i;
        const int b = m >> 11;           // /2048
        const int s = m & 2047;
        #pragma unroll
        for (int j = 0; j < 4; ++j) {
            const int e  = e0 + 4 * tx + j;
            const int qi = e >> 10;          // 0..2
            const int h  = (e >> 6) & 15;    // head
            const int hd = e & 63;
            qkvbuf[((size_t)(qi * 64 + b * 16 + h) * SEQ + s) * 64 + hd] = acc[i][j];
        }
    }
}

// ---------------------------------------------------------------------------
// Flash attention, fp32. One block per (bh, 64-query tile). 256 threads.
// ---------------------------------------------------------------------------
__global__ __launch_bounds__(256) void attn_kernel(const float* __restrict__ qkv,
                                                   float* __restrict__ attn_out) {
    __shared__ float Qt[64][68];     // Q transposed: Qt[d][q]
    __shared__ float KtPt[64][68];   // K transposed Kt[d][k]; reused as Pt[k][q]
    __shared__ float Vs[64][68];     // V natural: Vs[k][d]

    const int t  = threadIdx.x;
    const int q0 = blockIdx.x * 64;
    const int bh = blockIdx.y;                  // b*16 + h
    const float* Q = qkv + (size_t)(bh)       * SEQ * 64;
    const float* K = qkv + (size_t)(64 + bh)  * SEQ * 64;
    const float* V = qkv + (size_t)(128 + bh) * SEQ * 64;

    const int lq = t >> 6;    // wave id 0..3
    const int ld = t & 63;    // lane = dim

    // stage Q transposed (read coalesced, write strided; one-time)
    #pragma unroll
    for (int r = 0; r < 16; ++r) {
        const int q = r * 4 + lq;
        Qt[ld][q] = Q[(size_t)(q0 + q) * 64 + ld];
    }

    const int ty = t >> 4, tx = t & 15;
    float o[4][4] = {};
    float mi[4], li[4];
    #pragma unroll
    for (int i = 0; i < 4; ++i) { mi[i] = NEG_BIG; li[i] = 0.f; }

    for (int kt = 0; kt < SEQ / 64; ++kt) {
        const int k0 = kt * 64;
        __syncthreads();  // prev PV reads of KtPt/Vs done (also covers Qt init)
        #pragma unroll
        for (int r = 0; r < 16; ++r) {
            const int kx = r * 4 + lq;
            const float kvv = K[(size_t)(k0 + kx) * 64 + ld];
            const float vvv = V[(size_t)(k0 + kx) * 64 + ld];
            KtPt[ld][kx] = kvv;   // transposed
            Vs[kx][ld]   = vvv;   // natural
        }
        __syncthreads();

        // S[q=4ty+i][k=4tx+j] = sum_d Qt[d][q] * Kt[d][k]
        float s[4][4] = {};
        #pragma unroll 16
        for (int d = 0; d < 64; ++d) {
            const float4 a4 = *(const float4*)&Qt[d][4 * ty];
            const float4 b4 = *(const float4*)&KtPt[d][4 * tx];
            const float a[4] = {a4.x, a4.y, a4.z, a4.w};
            const float b[4] = {b4.x, b4.y, b4.z, b4.w};
            #pragma unroll
            for (int i = 0; i < 4; ++i)
                #pragma unroll
                for (int j = 0; j < 4; ++j)
                    s[i][j] = fmaf(a[i], b[j], s[i][j]);
        }

        // online softmax (per q-row; 16 tx lanes per row redundantly)
        #pragma unroll
        for (int i = 0; i < 4; ++i) {
            #pragma unroll
            for (int j = 0; j < 4; ++j) s[i][j] *= SCALE;
            float rm = fmaxf(fmaxf(s[i][0], s[i][1]), fmaxf(s[i][2], s[i][3]));
            rm = fmaxf(rm, __shfl_xor(rm, 1));
            rm = fmaxf(rm, __shfl_xor(rm, 2));
            rm = fmaxf(rm, __shfl_xor(rm, 4));
            rm = fmaxf(rm, __shfl_xor(rm, 8));
            const float mnew = fmaxf(mi[i], rm);
            const float corr = __expf(mi[i] - mnew);
            float rs = 0.f;
            #pragma unroll
            for (int j = 0; j < 4; ++j) {
                s[i][j] = __expf(s[i][j] - mnew);
                rs += s[i][j];
            }
            rs += __shfl_xor(rs, 1);
            rs += __shfl_xor(rs, 2);
            rs += __shfl_xor(rs, 4);
            rs += __shfl_xor(rs, 8);
            li[i] = li[i] * corr + rs;
            mi[i] = mnew;
            #pragma unroll
            for (int j = 0; j < 4; ++j) o[i][j] *= corr;
        }

        __syncthreads();  // everyone done reading Kt before overwriting with Pt
        #pragma unroll
        for (int j = 0; j < 4; ++j) {
            const float4 pv = make_float4(s[0][j], s[1][j], s[2][j], s[3][j]);
            *(float4*)&KtPt[4 * tx + j][4 * ty] = pv;   // Pt[k][q]
        }
        __syncthreads();

        // O[q=4ty+i][dc=4tx+j] += sum_k Pt[k][q] * Vs[k][dc]
        #pragma unroll 16
        for (int k = 0; k < 64; ++k) {
            const float4 p4 = *(const float4*)&KtPt[k][4 * ty];
            const float4 v4 = *(const float4*)&Vs[k][4 * tx];
            const float p[4] = {p4.x, p4.y, p4.z, p4.w};
            const float v[4] = {v4.x, v4.y, v4.z, v4.w};
            #pragma unroll
            for (int i = 0; i < 4; ++i)
                #pragma unroll
                for (int j = 0; j < 4; ++j)
                    o[i][j] = fmaf(p[i], v[j], o[i][j]);
        }
    }

    // epilogue: write [b, s, h*64+hd]
    const int b = bh >> 4, h = bh & 15;
    #pragma unroll
    for (int i = 0; i < 4; ++i) {
        const float inv = 1.0f / li[i];
        const size_t row = (size_t)b * SEQ + q0 + 4 * ty + i;
        #pragma unroll
        for (int j = 0; j < 4; ++j)
            attn_out[row * DIM + h * 64 + 4 * tx + j] = o[i][j] * inv;
    }
}

// ---------------------------------------------------------------------------
// Output projection: out[m,e] = sum_d A[m,d] * Wout[e,d] + bias[e]
// ---------------------------------------------------------------------------
__global__ __launch_bounds__(256) void out_gemm(const float* __restrict__ A,
                                                const float* __restrict__ W,
                                                const float* __restrict__ bias,
                                                float* __restrict__ out) {
    __shared__ float As[16][68];
    __shared__ float Bs[16][68];
    const int t  = threadIdx.x;
    const int m0 = blockIdx.y * 64;
    const int e0 = blockIdx.x * 64;
    const int ty = t >> 4, tx = t & 15;
    const int lr = t >> 2;
    const int lk = (t & 3) * 4;

    float acc[4][4] = {};

    for (int k0 = 0; k0 < DIM; k0 += 16) {
        __syncthreads();
        const float4 av = *(const float4*)&A[(size_t)(m0 + lr) * DIM + k0 + lk];
        const float4 bv = *(const float4*)&W[(size_t)(e0 + lr) * DIM + k0 + lk];
        As[lk + 0][lr] = av.x; As[lk + 1][lr] = av.y;
        As[lk + 2][lr] = av.z; As[lk + 3][lr] = av.w;
        Bs[lk + 0][lr] = bv.x; Bs[lk + 1][lr] = bv.y;
        Bs[lk + 2][lr] = bv.z; Bs[lk + 3][lr] = bv.w;
        __syncthreads();
        #pragma unroll
        for (int kk = 0; kk < 16; ++kk) {
            const float4 a4 = *(const float4*)&As[kk][4 * ty];
            const float4 b4 = *(const float4*)&Bs[kk][4 * tx];
            const float a[4] = {a4.x, a4.y, a4.z, a4.w};
            const float b[4] = {b4.x, b4.y, b4.z, b4.w};
            #pragma unroll
            for (int i = 0; i < 4; ++i)
                #pragma unroll
                for (int j = 0; j < 4; ++j)
                    acc[i][j] = fmaf(a[i], b[j], acc[i][j]);
        }
    }

    #pragma unroll
    for (int i = 0; i < 4; ++i) {
        const size_t m = m0 + 4 * ty + i;
        #pragma unroll
        for (int j = 0; j < 4; ++j) {
            const int e = e0 + 4 * tx + j;
            out[m * DIM + e] = acc[i][j] + bias[e];
        }
    }
}

// ---------------------------------------------------------------------------
extern "C" void kernel_launch(void* const* d_in, const int* in_sizes, int n_in,
                              void* d_out, int out_size, void* d_ws, size_t ws_size,
                              hipStream_t stream) {
    const float* x     = (const float*)d_in[0];   // [4,2048,1024]
    const float* w_qkv = (const float*)d_in[1];   // [3072,1024]
    const float* w_out = (const float*)d_in[2];   // [1024,1024]
    const float* b_out = (const float*)d_in[3];   // [1024]
    float* out = (float*)d_out;

    float* qkvbuf = (float*)d_ws;                        // 3*64*2048*64 = 25165824 floats (96 MB)
    float* attn   = qkvbuf + (size_t)3 * 64 * SEQ * 64;  // 64*2048*64  =  8388608 floats (32 MB)

    qkv_gemm<<<dim3(48, 128), 256, 0, stream>>>(x, w_qkv, qkvbuf);
    attn_kernel<<<dim3(SEQ / 64, 64), 256, 0, stream>>>(qkvbuf, attn);
    out_gemm<<<dim3(16, 128), 256, 0, stream>>>(attn, w_out, b_out, out);
}

// Round 2
// 359.034 us; speedup vs baseline: 5.5655x; 5.5655x over previous
//
#include <hip/hip_runtime.h>

#define DIM 1024
#define SEQ 2048
#define SCALE 0.125f

typedef unsigned short ushort_t;
typedef unsigned int u32;
typedef __attribute__((ext_vector_type(8))) short short8;
typedef __attribute__((ext_vector_type(8))) unsigned short ushort8;
typedef __attribute__((ext_vector_type(4))) float f32x4;

__device__ __forceinline__ ushort_t f2bf(float x) {
    u32 u = __float_as_uint(x);
    u32 r = (u + 0x7fffu + ((u >> 16) & 1u)) >> 16;
    return (ushort_t)r;
}

__device__ __forceinline__ void gload16(const void* g, void* l) {
    __builtin_amdgcn_global_load_lds(
        (const __attribute__((address_space(1))) u32*)g,
        (__attribute__((address_space(3))) u32*)l, 16, 0, 0);
}

// XOR-swizzled element index within a [rows][64-bf16] tile (8-elem groups)
__device__ __forceinline__ int swz8(int row, int col) {
    return row * 64 + ((((col >> 3) ^ (row & 7)) << 3) | (col & 7));
}

// ---------------------------------------------------------------------------
// fp32 -> bf16 conversion (vectorized, grid-stride)
// ---------------------------------------------------------------------------
__global__ __launch_bounds__(256) void cvt_bf16(const float* __restrict__ in,
                                                ushort_t* __restrict__ out, int n8) {
    for (int i = blockIdx.x * blockDim.x + threadIdx.x; i < n8; i += gridDim.x * blockDim.x) {
        const float4 a = ((const float4*)in)[2 * i];
        const float4 b = ((const float4*)in)[2 * i + 1];
        ushort8 o;
        o[0] = f2bf(a.x); o[1] = f2bf(a.y); o[2] = f2bf(a.z); o[3] = f2bf(a.w);
        o[4] = f2bf(b.x); o[5] = f2bf(b.y); o[6] = f2bf(b.z); o[7] = f2bf(b.w);
        ((ushort8*)out)[i] = o;
    }
}

// ---------------------------------------------------------------------------
// bf16 GEMM, m97 structure: C[m,n] = sum_k A[m,k] * B[n,k]  (B^T layout)
// 128x128 tile, BK=64, 4 waves, global_load_lds width 16, linear LDS.
// EPI 0: scatter bf16 into qkv buffer [3][bh][s][64]
// EPI 1: fp32 out + bias
// ---------------------------------------------------------------------------
template <int EPI>
__global__ __launch_bounds__(256) void gemm_bt(const ushort_t* __restrict__ A,
                                               const ushort_t* __restrict__ B,
                                               const float* __restrict__ bias,
                                               ushort_t* __restrict__ outb,
                                               float* __restrict__ outf) {
    __shared__ ushort_t As[128 * 64];
    __shared__ ushort_t Bs[128 * 64];
    const int t = threadIdx.x;
    const int m0 = blockIdx.y * 128, n0 = blockIdx.x * 128;
    const int w = t >> 6, lane = t & 63, k15 = lane & 15, g = lane >> 4;
    const int wm = (w >> 1) * 64, wn = (w & 1) * 64;
    const int srow = t >> 3, scol = (t & 7) * 8;

    f32x4 acc[4][4] = {};

    for (int k0 = 0; k0 < 1024; k0 += 64) {
        __syncthreads();
        #pragma unroll
        for (int i = 0; i < 4; ++i) {
            gload16(&A[(size_t)(m0 + i * 32 + srow) * 1024 + k0 + scol],
                    ((char*)As) + i * 4096 + t * 16);
            gload16(&B[(size_t)(n0 + i * 32 + srow) * 1024 + k0 + scol],
                    ((char*)Bs) + i * 4096 + t * 16);
        }
        __syncthreads();
        #pragma unroll
        for (int ks = 0; ks < 2; ++ks) {
            short8 af[4], bf[4];
            #pragma unroll
            for (int i = 0; i < 4; ++i) {
                af[i] = *(const short8*)&As[(wm + i * 16 + k15) * 64 + ks * 32 + g * 8];
                bf[i] = *(const short8*)&Bs[(wn + i * 16 + k15) * 64 + ks * 32 + g * 8];
            }
            #pragma unroll
            for (int mi = 0; mi < 4; ++mi)
                #pragma unroll
                for (int ni = 0; ni < 4; ++ni)
                    acc[mi][ni] = __builtin_amdgcn_mfma_f32_16x16x32_bf16(
                        af[mi], bf[ni], acc[mi][ni], 0, 0, 0);
        }
    }

    if (EPI == 0) {
        #pragma unroll
        for (int mi = 0; mi < 4; ++mi) {
            #pragma unroll
            for (int r = 0; r < 4; ++r) {
                const int m = m0 + wm + mi * 16 + g * 4 + r;
                const int b = m >> 11, s = m & 2047;
                #pragma unroll
                for (int ni = 0; ni < 4; ++ni) {
                    const int e = n0 + wn + ni * 16 + k15;
                    const int qi = e >> 10, h = (e >> 6) & 15, hd = e & 63;
                    outb[((size_t)(qi * 64 + b * 16 + h) * SEQ + s) * 64 + hd] =
                        f2bf(acc[mi][ni][r]);
                }
            }
        }
    } else {
        #pragma unroll
        for (int mi = 0; mi < 4; ++mi) {
            #pragma unroll
            for (int r = 0; r < 4; ++r) {
                const size_t m = m0 + wm + mi * 16 + g * 4 + r;
                #pragma unroll
                for (int ni = 0; ni < 4; ++ni) {
                    const int e = n0 + wn + ni * 16 + k15;
                    outf[m * 1024 + e] = acc[mi][ni][r] + bias[e];
                }
            }
        }
    }
}

// ---------------------------------------------------------------------------
// Flash attention, bf16 MFMA. 256 threads = 4 waves; wave owns 32 q-rows.
// QBLK=128, KVBLK=64. K staged via pre-swizzled global_load_lds; V reg-staged
// transposed; P through per-wave LDS. All LDS tiles XOR-swizzled (8-elem).
// ---------------------------------------------------------------------------
__global__ __launch_bounds__(256) void attn_mfma(const ushort_t* __restrict__ qkv,
                                                 ushort_t* __restrict__ aout) {
    __shared__ ushort_t Ks[64 * 64];
    __shared__ ushort_t Vt[64 * 64];   // transposed: [d][key]
    __shared__ ushort_t Pl[4 * 32 * 64];

    const int t = threadIdx.x, w = t >> 6, lane = t & 63;
    const int k15 = lane & 15, g = lane >> 4;
    const int q0 = blockIdx.x * 128, bh = blockIdx.y;
    const ushort_t* Qp = qkv + (size_t)bh * SEQ * 64;
    const ushort_t* Kp = qkv + (size_t)(64 + bh) * SEQ * 64;
    const ushort_t* Vp = qkv + (size_t)(128 + bh) * SEQ * 64;
    const int wq0 = q0 + w * 32;
    ushort_t* Pw = Pl + w * (32 * 64);

    // Q fragments, resident whole kernel
    short8 qf[2][2];
    #pragma unroll
    for (int mt = 0; mt < 2; ++mt)
        #pragma unroll
        for (int ks = 0; ks < 2; ++ks)
            qf[mt][ks] = *(const short8*)&Qp[(size_t)(wq0 + mt * 16 + k15) * 64 + ks * 32 + g * 8];

    f32x4 o[2][4] = {};
    float mi[2][4], li[2][4];
    #pragma unroll
    for (int mt = 0; mt < 2; ++mt)
        #pragma unroll
        for (int r = 0; r < 4; ++r) { mi[mt][r] = -1e30f; li[mt][r] = 0.f; }

    for (int kt = 0; kt < SEQ / 64; ++kt) {
        const int kb = kt * 64;
        __syncthreads();
        // stage K: linear LDS dest, pre-swizzled global source
        #pragma unroll
        for (int i = 0; i < 2; ++i) {
            const int row = i * 32 + (t >> 3);
            const int scb = (t & 7) ^ (row & 7);
            gload16(&Kp[(size_t)(kb + row) * 64 + scb * 8],
                    ((char*)Ks) + i * 4096 + t * 16);
        }
        // stage V transposed (reg -> swizzled ds writes)
        {
            const int key = t & 63;
            short8 v0 = *(const short8*)&Vp[(size_t)(kb + key) * 64 + (t >> 6) * 8];
            short8 v1 = *(const short8*)&Vp[(size_t)(kb + key) * 64 + (t >> 6) * 8 + 32];
            #pragma unroll
            for (int j = 0; j < 8; ++j) {
                Vt[swz8((t >> 6) * 8 + j, key)]      = (ushort_t)v0[j];
                Vt[swz8((t >> 6) * 8 + 32 + j, key)] = (ushort_t)v1[j];
            }
        }
        __syncthreads();

        // QK^T: S[32 q][64 key]
        f32x4 s[2][4] = {};
        #pragma unroll
        for (int ks = 0; ks < 2; ++ks) {
            short8 kf[4];
            #pragma unroll
            for (int nt = 0; nt < 4; ++nt)
                kf[nt] = *(const short8*)&Ks[swz8(nt * 16 + k15, ks * 32 + g * 8)];
            #pragma unroll
            for (int mt = 0; mt < 2; ++mt)
                #pragma unroll
                for (int nt = 0; nt < 4; ++nt)
                    s[mt][nt] = __builtin_amdgcn_mfma_f32_16x16x32_bf16(
                        qf[mt][ks], kf[nt], s[mt][nt], 0, 0, 0);
        }

        // online softmax + P -> LDS (bf16)
        #pragma unroll
        for (int mt = 0; mt < 2; ++mt) {
            #pragma unroll
            for (int r = 0; r < 4; ++r) {
                float x0 = s[mt][0][r] * SCALE, x1 = s[mt][1][r] * SCALE;
                float x2 = s[mt][2][r] * SCALE, x3 = s[mt][3][r] * SCALE;
                float rm = fmaxf(fmaxf(x0, x1), fmaxf(x2, x3));
                rm = fmaxf(rm, __shfl_xor(rm, 1));
                rm = fmaxf(rm, __shfl_xor(rm, 2));
                rm = fmaxf(rm, __shfl_xor(rm, 4));
                rm = fmaxf(rm, __shfl_xor(rm, 8));
                const float mnew = fmaxf(mi[mt][r], rm);
                const float corr = __expf(mi[mt][r] - mnew);
                mi[mt][r] = mnew;
                const float e0 = __expf(x0 - mnew), e1 = __expf(x1 - mnew);
                const float e2 = __expf(x2 - mnew), e3 = __expf(x3 - mnew);
                float rs = (e0 + e1) + (e2 + e3);
                rs += __shfl_xor(rs, 1);
                rs += __shfl_xor(rs, 2);
                rs += __shfl_xor(rs, 4);
                rs += __shfl_xor(rs, 8);
                li[mt][r] = li[mt][r] * corr + rs;
                const int row = mt * 16 + g * 4 + r;
                Pw[swz8(row, 0 * 16 + k15)] = f2bf(e0);
                Pw[swz8(row, 1 * 16 + k15)] = f2bf(e1);
                Pw[swz8(row, 2 * 16 + k15)] = f2bf(e2);
                Pw[swz8(row, 3 * 16 + k15)] = f2bf(e3);
                #pragma unroll
                for (int dt = 0; dt < 4; ++dt) o[mt][dt][r] *= corr;
            }
        }

        // PV: O[32 q][64 d] += P[32][64] * V[64][64]   (B^T = Vt)
        #pragma unroll
        for (int ks = 0; ks < 2; ++ks) {
            short8 pa[2], vb[4];
            #pragma unroll
            for (int mt = 0; mt < 2; ++mt)
                pa[mt] = *(const short8*)&Pw[swz8(mt * 16 + k15, ks * 32 + g * 8)];
            #pragma unroll
            for (int dt = 0; dt < 4; ++dt)
                vb[dt] = *(const short8*)&Vt[swz8(dt * 16 + k15, ks * 32 + g * 8)];
            #pragma unroll
            for (int mt = 0; mt < 2; ++mt)
                #pragma unroll
                for (int dt = 0; dt < 4; ++dt)
                    o[mt][dt] = __builtin_amdgcn_mfma_f32_16x16x32_bf16(
                        pa[mt], vb[dt], o[mt][dt], 0, 0, 0);
        }
    }

    // epilogue: out rows [b, s, h*64 + d], bf16
    const int b = bh >> 4, h = bh & 15;
    #pragma unroll
    for (int mt = 0; mt < 2; ++mt) {
        #pragma unroll
        for (int r = 0; r < 4; ++r) {
            const float inv = 1.0f / li[mt][r];
            const int q = wq0 + mt * 16 + g * 4 + r;
            const size_t rowo = ((size_t)b * SEQ + q) * DIM + h * 64;
            #pragma unroll
            for (int dt = 0; dt < 4; ++dt)
                aout[rowo + dt * 16 + k15] = f2bf(o[mt][dt][r] * inv);
        }
    }
}

// ---------------------------------------------------------------------------
extern "C" void kernel_launch(void* const* d_in, const int* in_sizes, int n_in,
                              void* d_out, int out_size, void* d_ws, size_t ws_size,
                              hipStream_t stream) {
    const float* x     = (const float*)d_in[0];   // [4,2048,1024]
    const float* w_qkv = (const float*)d_in[1];   // [3072,1024]
    const float* w_out = (const float*)d_in[2];   // [1024,1024]
    const float* b_out = (const float*)d_in[3];   // [1024]
    float* out = (float*)d_out;

    char* ws = (char*)d_ws;
    ushort_t* xb    = (ushort_t*)ws;                          // 16 MB
    ushort_t* wqkvb = (ushort_t*)(ws + (size_t)16 * 1024 * 1024);   // 6 MB
    ushort_t* woutb = (ushort_t*)(ws + (size_t)22 * 1024 * 1024);   // 2 MB
    ushort_t* qkvb  = (ushort_t*)(ws + (size_t)24 * 1024 * 1024);   // 48 MB: [3][64][2048][64]
    ushort_t* aob   = (ushort_t*)(ws + (size_t)72 * 1024 * 1024);   // 16 MB: [8192][1024]

    cvt_bf16<<<1024, 256, 0, stream>>>(x,     xb,    8192 * 1024 / 8);
    cvt_bf16<<<512,  256, 0, stream>>>(w_qkv, wqkvb, 3072 * 1024 / 8);
    cvt_bf16<<<256,  256, 0, stream>>>(w_out, woutb, 1024 * 1024 / 8);

    gemm_bt<0><<<dim3(24, 64), 256, 0, stream>>>(xb, wqkvb, nullptr, qkvb, nullptr);
    attn_mfma<<<dim3(16, 64), 256, 0, stream>>>(qkvb, aob);
    gemm_bt<1><<<dim3(8, 64), 256, 0, stream>>>(aob, woutb, b_out, nullptr, out);
}